// Round 3
// baseline (541.948 us; speedup 1.0000x reference)
//
#include <hip/hip_runtime.h>
#include <stdint.h>

#define S_DIM 8192
#define K_DIM 4096
#define N_DIM 4096

#define BM 128
#define BN 128
#define BK 64

typedef int v4i __attribute__((ext_vector_type(4)));

// ---------------------------------------------------------------------------
// Pack int32-widened int8 values down to contiguous int8.
__global__ void pack_i8(const int* __restrict__ src, int* __restrict__ dst,
                        int n4) {
    int i = blockIdx.x * blockDim.x + threadIdx.x;
    if (i >= n4) return;
    int4 a = ((const int4*)src)[i];
    dst[i] = (a.x & 0xFF) | ((a.y & 0xFF) << 8) | ((a.z & 0xFF) << 16)
           | ((a.w & 0xFF) << 24);
}

// ---------------------------------------------------------------------------
__global__ void copy_sy(const float* __restrict__ sy, float* __restrict__ out) {
    int i = blockIdx.x * blockDim.x + threadIdx.x;
    if (i < S_DIM) out[(size_t)S_DIM * N_DIM + i] = sy[i];
}

// ---------------------------------------------------------------------------
__device__ __forceinline__ void g2lds16(const void* g, void* l) {
    __builtin_amdgcn_global_load_lds((const __attribute__((address_space(1))) void*)g,
                                     (__attribute__((address_space(3))) void*)l,
                                     16, 0, 0);
}

// ---------------------------------------------------------------------------
// 128x128 tile i8 MFMA GEMM. A (x) staged in LDS (XOR-swizzled, conflict-free);
// B (w) fragments streamed DIRECTLY global->VGPR each K-iter — halves LDS pipe
// traffic (the measured limiter: 48KB/iter vs 82cy MFMA). B loads are issued
// before the staging barriers so the barrier's vmcnt drain hides their latency.
// Grid: blockIdx.x = bm (fast axis) so concurrent blocks on an XCD share bn ->
// W-tile (512KB) stays hot in that XCD's 4MB L2.
__launch_bounds__(256)
__global__ void gemm_i8(const signed char* __restrict__ xp,
                        const signed char* __restrict__ wp,
                        const float* __restrict__ sx,
                        const float* __restrict__ sw,
                        const float* __restrict__ sy,
                        float* __restrict__ out) {
    __shared__ __align__(16) signed char As[BM * BK];   // [row][k], stride 64B

    const int tid  = threadIdx.x;
    const int lane = tid & 63;
    const int quad = lane >> 4;    // 0..3 -> 16B k-chunk
    const int l16  = lane & 15;    // row (A) / col (B) within 16
    const int wave = tid >> 6;     // 0..3
    const int wm = wave >> 1;      // wave row (2x2)
    const int wn = wave & 1;       // wave col
    const int bm = blockIdx.x;     // fast axis: consecutive blocks share bn
    const int bn = blockIdx.y;

    const signed char* aG = xp + (size_t)(bm * BM) * K_DIM;
    // per-lane W base: row (n) = bn*BN + wn*64 + nt*16 + l16, byte k = quad*16
    const signed char* bW = wp + (size_t)(bn * BN + wn * 64 + l16) * K_DIM
                               + (quad << 4);

    const int csw = ((l16 >> 1) & 3);  // fragment-read swizzle component

    v4i acc[4][4];
#pragma unroll
    for (int i = 0; i < 4; i++)
#pragma unroll
        for (int j = 0; j < 4; j++) acc[i][j] = 0;

    for (int kk = 0; kk < K_DIM; kk += BK) {
        // B fragments for this K-slice: issue FIRST so global latency is
        // covered by the staging barrier's vmcnt drain.
        v4i bf[4];
#pragma unroll
        for (int nt = 0; nt < 4; nt++)
            bf[nt] = *(const v4i*)(bW + (size_t)(nt * 16) * K_DIM + kk);

        __syncthreads();  // protect As from previous iteration's readers
#pragma unroll
        for (int i = 0; i < 2; i++) {
            int li  = i * 256 + tid;           // 512 chunks of 16B
            int row = li >> 2;                 // tile row (0..127)
            int c   = li & 3;                  // LDS chunk slot
            int g   = c ^ ((row >> 1) & 3);    // swizzled global chunk
            g2lds16(aG + (size_t)row * K_DIM + kk + (g << 4), As + li * 16);
        }
        __syncthreads();

        v4i af[4];
#pragma unroll
        for (int t = 0; t < 4; t++)
            af[t] = *(const v4i*)(As + (wm * 64 + t * 16 + l16) * BK
                                     + ((quad ^ csw) << 4));
#pragma unroll
        for (int mt = 0; mt < 4; mt++)
#pragma unroll
            for (int nt = 0; nt < 4; nt++)
                acc[mt][nt] = __builtin_amdgcn_mfma_i32_16x16x64_i8(
                    af[mt], bf[nt], acc[mt][nt], 0, 0, 0);
    }

    // Epilogue: C/D layout: col = lane&15, row = quad*4 + reg.
    const int s_base = bm * BM + wm * 64;
    const int n_base = bn * BN + wn * 64;
#pragma unroll
    for (int mt = 0; mt < 4; mt++) {
#pragma unroll
        for (int r = 0; r < 4; r++) {
            int s = s_base + mt * 16 + quad * 4 + r;
            float rs = sx[s] / sy[s];
            float* orow = out + (size_t)s * N_DIM;
#pragma unroll
            for (int nt = 0; nt < 4; nt++) {
                int n = n_base + nt * 16 + l16;
                float v = rintf((float)acc[mt][nt][r] * (rs * sw[n]));
                v = fminf(fmaxf(v, -128.f), 127.f);
                orow[n] = v;
            }
        }
    }
}

// ---------------------------------------------------------------------------
// Correctness fallback if the workspace is too small for packed operands.
__global__ void gemm_naive(const int* __restrict__ x, const int* __restrict__ w,
                           const float* __restrict__ sx, const float* __restrict__ sw,
                           const float* __restrict__ sy, float* __restrict__ out) {
    int n = blockIdx.x * blockDim.x + threadIdx.x;
    int s = blockIdx.y;
    const int4* xr = (const int4*)(x + (size_t)s * K_DIM);
    const int4* wr = (const int4*)(w + (size_t)n * K_DIM);
    int acc = 0;
    for (int k = 0; k < K_DIM / 4; k++) {
        int4 a = xr[k], b = wr[k];
        acc += a.x * b.x + a.y * b.y + a.z * b.z + a.w * b.w;
    }
    float v = rintf((float)acc * (sx[s] / sy[s] * sw[n]));
    out[(size_t)s * N_DIM + n] = fminf(fmaxf(v, -128.f), 127.f);
}

// ---------------------------------------------------------------------------
extern "C" void kernel_launch(void* const* d_in, const int* in_sizes, int n_in,
                              void* d_out, int out_size, void* d_ws, size_t ws_size,
                              hipStream_t stream) {
    const int*   x  = (const int*)d_in[0];     // [S, K] int8 values widened to int32
    const int*   wq = (const int*)d_in[1];     // [N, K]
    const float* sx = (const float*)d_in[2];   // [S]
    const float* sw = (const float*)d_in[3];   // [N]
    const float* sy = (const float*)d_in[4];   // [S]
    float* out = (float*)d_out;                // [S*N out_q] ++ [S scale_y], float32

    copy_sy<<<dim3((S_DIM + 255) / 256), dim3(256), 0, stream>>>(sy, out);

    const size_t need = (size_t)S_DIM * K_DIM + (size_t)N_DIM * K_DIM;  // 48 MiB
    if (ws_size >= need) {
        signed char* xp = (signed char*)d_ws;
        signed char* wp = xp + (size_t)S_DIM * K_DIM;
        pack_i8<<<dim3(S_DIM * K_DIM / 4 / 256), dim3(256), 0, stream>>>(
            x, (int*)xp, S_DIM * K_DIM / 4);
        pack_i8<<<dim3(N_DIM * K_DIM / 4 / 256), dim3(256), 0, stream>>>(
            wq, (int*)wp, N_DIM * K_DIM / 4);
        // grid: x = bm (S/BM = 64, fast), y = bn (N/BN = 32)
        gemm_i8<<<dim3(S_DIM / BM, N_DIM / BN), dim3(256), 0, stream>>>(
            xp, wp, sx, sw, sy, out);
    } else {
        gemm_naive<<<dim3(N_DIM / 256, S_DIM), dim3(256), 0, stream>>>(
            x, wq, sx, sw, sy, out);
    }
}

// Round 4
// 424.148 us; speedup vs baseline: 1.2777x; 1.2777x over previous
//
#include <hip/hip_runtime.h>
#include <stdint.h>

#define S_DIM 8192
#define K_DIM 4096
#define N_DIM 4096

#define BM 128
#define BN 128
#define BK 128   // bytes of K per staging iteration (2 MFMA k-steps of 64)

typedef int v4i __attribute__((ext_vector_type(4)));

// ---------------------------------------------------------------------------
// Pack int32-widened int8 values down to contiguous int8.
__global__ void pack_i8(const int* __restrict__ src, int* __restrict__ dst,
                        int n4) {
    int i = blockIdx.x * blockDim.x + threadIdx.x;
    if (i >= n4) return;
    int4 a = ((const int4*)src)[i];
    dst[i] = (a.x & 0xFF) | ((a.y & 0xFF) << 8) | ((a.z & 0xFF) << 16)
           | ((a.w & 0xFF) << 24);
}

// ---------------------------------------------------------------------------
__global__ void copy_sy(const float* __restrict__ sy, float* __restrict__ out) {
    int i = blockIdx.x * blockDim.x + threadIdx.x;
    if (i < S_DIM) out[(size_t)S_DIM * N_DIM + i] = sy[i];
}

// ---------------------------------------------------------------------------
__device__ __forceinline__ void g2lds16(const void* g, void* l) {
    __builtin_amdgcn_global_load_lds((const __attribute__((address_space(1))) void*)g,
                                     (__attribute__((address_space(3))) void*)l,
                                     16, 0, 0);
}

// ---------------------------------------------------------------------------
// 128x128 tile i8 MFMA GEMM, both operands staged via global_load_lds (R2
// structure — register-streaming B regressed: __syncthreads drains vmcnt(0),
// exposing global->VGPR latency every iter). BK=128 BYTES per barrier pair
// (32 MFMAs/wave/iter) to match the verified m97 staged-bytes:MFMA balance;
// halves barrier-drain overhead per MFMA vs BK=64.
// LDS rows are 8 x 16B chunks, XOR-swizzled: slot = chunk ^ (row&7), so
// fragment ds_read_b128 is 2-lanes/bank-group (free, m136).
__launch_bounds__(256)
__global__ void gemm_i8(const signed char* __restrict__ xp,
                        const signed char* __restrict__ wp,
                        const float* __restrict__ sx,
                        const float* __restrict__ sw,
                        const float* __restrict__ sy,
                        float* __restrict__ out) {
    __shared__ __align__(16) signed char As[BM * BK];   // 16 KB
    __shared__ __align__(16) signed char Bs[BN * BK];   // 16 KB

    const int tid  = threadIdx.x;
    const int lane = tid & 63;
    const int quad = lane >> 4;    // 0..3 -> 16B k-chunk within a 64B k-step
    const int l16  = lane & 15;    // row (A) / col (B) within 16
    const int wave = tid >> 6;     // 0..3
    const int wm = wave >> 1;      // wave row (2x2)
    const int wn = wave & 1;       // wave col
    const int bn = blockIdx.x;     // fast axis (as in R2's best run)
    const int bm = blockIdx.y;

    const signed char* aG = xp + (size_t)(bm * BM) * K_DIM;
    const signed char* bG = wp + (size_t)(bn * BN) * K_DIM;

    const int csw = l16 & 7;       // fragment-read swizzle component

    v4i acc[4][4];
#pragma unroll
    for (int i = 0; i < 4; i++)
#pragma unroll
        for (int j = 0; j < 4; j++) acc[i][j] = 0;

    for (int kk = 0; kk < K_DIM; kk += BK) {
        __syncthreads();  // protect LDS from previous iteration's readers
#pragma unroll
        for (int i = 0; i < 4; i++) {
            // 1024 chunks of 16B per operand tile (128 rows x 8 chunks)
            int li  = i * 256 + tid;
            int row = li >> 3;                 // tile row (0..127)
            int c   = li & 7;                  // LDS chunk slot
            int g   = c ^ (row & 7);           // swizzled global chunk
            g2lds16(aG + (size_t)row * K_DIM + kk + (g << 4), As + li * 16);
            g2lds16(bG + (size_t)row * K_DIM + kk + (g << 4), Bs + li * 16);
        }
        __syncthreads();  // vmcnt(0) drain: staging complete

#pragma unroll
        for (int ks = 0; ks < 2; ks++) {       // two 64B k-steps per stage
            const int slot = ((ks << 2) | quad);
            v4i af[4], bf[4];
#pragma unroll
            for (int t = 0; t < 4; t++) {
                af[t] = *(const v4i*)(As + (wm * 64 + t * 16 + l16) * BK
                                         + ((slot ^ csw) << 4));
                bf[t] = *(const v4i*)(Bs + (wn * 64 + t * 16 + l16) * BK
                                         + ((slot ^ csw) << 4));
            }
#pragma unroll
            for (int mt = 0; mt < 4; mt++)
#pragma unroll
                for (int nt = 0; nt < 4; nt++)
                    acc[mt][nt] = __builtin_amdgcn_mfma_i32_16x16x64_i8(
                        af[mt], bf[nt], acc[mt][nt], 0, 0, 0);
        }
    }

    // Epilogue: C/D layout: col = lane&15, row = quad*4 + reg.
    const int s_base = bm * BM + wm * 64;
    const int n_base = bn * BN + wn * 64;
#pragma unroll
    for (int mt = 0; mt < 4; mt++) {
#pragma unroll
        for (int r = 0; r < 4; r++) {
            int s = s_base + mt * 16 + quad * 4 + r;
            float rs = sx[s] / sy[s];
            float* orow = out + (size_t)s * N_DIM;
#pragma unroll
            for (int nt = 0; nt < 4; nt++) {
                int n = n_base + nt * 16 + l16;
                float v = rintf((float)acc[mt][nt][r] * (rs * sw[n]));
                v = fminf(fmaxf(v, -128.f), 127.f);
                orow[n] = v;
            }
        }
    }
}

// ---------------------------------------------------------------------------
// Correctness fallback if the workspace is too small for packed operands.
__global__ void gemm_naive(const int* __restrict__ x, const int* __restrict__ w,
                           const float* __restrict__ sx, const float* __restrict__ sw,
                           const float* __restrict__ sy, float* __restrict__ out) {
    int n = blockIdx.x * blockDim.x + threadIdx.x;
    int s = blockIdx.y;
    const int4* xr = (const int4*)(x + (size_t)s * K_DIM);
    const int4* wr = (const int4*)(w + (size_t)n * K_DIM);
    int acc = 0;
    for (int k = 0; k < K_DIM / 4; k++) {
        int4 a = xr[k], b = wr[k];
        acc += a.x * b.x + a.y * b.y + a.z * b.z + a.w * b.w;
    }
    float v = rintf((float)acc * (sx[s] / sy[s] * sw[n]));
    out[(size_t)s * N_DIM + n] = fminf(fmaxf(v, -128.f), 127.f);
}

// ---------------------------------------------------------------------------
extern "C" void kernel_launch(void* const* d_in, const int* in_sizes, int n_in,
                              void* d_out, int out_size, void* d_ws, size_t ws_size,
                              hipStream_t stream) {
    const int*   x  = (const int*)d_in[0];     // [S, K] int8 values widened to int32
    const int*   wq = (const int*)d_in[1];     // [N, K]
    const float* sx = (const float*)d_in[2];   // [S]
    const float* sw = (const float*)d_in[3];   // [N]
    const float* sy = (const float*)d_in[4];   // [S]
    float* out = (float*)d_out;                // [S*N out_q] ++ [S scale_y], float32

    copy_sy<<<dim3((S_DIM + 255) / 256), dim3(256), 0, stream>>>(sy, out);

    const size_t need = (size_t)S_DIM * K_DIM + (size_t)N_DIM * K_DIM;  // 48 MiB
    if (ws_size >= need) {
        signed char* xp = (signed char*)d_ws;
        signed char* wp = xp + (size_t)S_DIM * K_DIM;
        pack_i8<<<dim3(S_DIM * K_DIM / 4 / 256), dim3(256), 0, stream>>>(
            x, (int*)xp, S_DIM * K_DIM / 4);
        pack_i8<<<dim3(N_DIM * K_DIM / 4 / 256), dim3(256), 0, stream>>>(
            wq, (int*)wp, N_DIM * K_DIM / 4);
        gemm_i8<<<dim3(N_DIM / BN, S_DIM / BM), dim3(256), 0, stream>>>(
            xp, wp, sx, sw, sy, out);
    } else {
        gemm_naive<<<dim3(N_DIM / 256, S_DIM), dim3(256), 0, stream>>>(
            x, wq, sx, sw, sy, out);
    }
}

// Round 5
// 391.537 us; speedup vs baseline: 1.3842x; 1.0833x over previous
//
#include <hip/hip_runtime.h>
#include <stdint.h>

#define S_DIM 8192
#define K_DIM 4096
#define N_DIM 4096

#define BM 128
#define BN 256
#define BK 128   // bytes of K per staging stage (2 MFMA k-steps of 64)

typedef int v4i __attribute__((ext_vector_type(4)));

// ---------------------------------------------------------------------------
// One launch: pack x (int32->int8), pack w, and copy scale_y to the output
// tail. Pack destination is contiguous in ws: [x packed | w packed].
__global__ void prep(const int* __restrict__ x, const int* __restrict__ w,
                     const float* __restrict__ sy,
                     int* __restrict__ dst, float* __restrict__ out) {
    const int nx = S_DIM * K_DIM / 4;
    const int nw = N_DIM * K_DIM / 4;
    int i = blockIdx.x * 256 + threadIdx.x;
    if (i < nx) {
        int4 a = ((const int4*)x)[i];
        dst[i] = (a.x & 0xFF) | ((a.y & 0xFF) << 8) | ((a.z & 0xFF) << 16)
               | ((a.w & 0xFF) << 24);
    } else if (i < nx + nw) {
        int4 a = ((const int4*)w)[i - nx];
        dst[i] = (a.x & 0xFF) | ((a.y & 0xFF) << 8) | ((a.z & 0xFF) << 16)
               | ((a.w & 0xFF) << 24);
    } else {
        int j = i - nx - nw;
        if (j < S_DIM) out[(size_t)S_DIM * N_DIM + j] = sy[j];
    }
}

// scale_y tail only (used by the no-workspace fallback path)
__global__ void copy_sy(const float* __restrict__ sy, float* __restrict__ out) {
    int i = blockIdx.x * blockDim.x + threadIdx.x;
    if (i < S_DIM) out[(size_t)S_DIM * N_DIM + i] = sy[i];
}

// ---------------------------------------------------------------------------
__device__ __forceinline__ void g2lds16(const void* g, void* l) {
    __builtin_amdgcn_global_load_lds((const __attribute__((address_space(1))) void*)g,
                                     (__attribute__((address_space(3))) void*)l,
                                     16, 0, 0);
}

// ---------------------------------------------------------------------------
// 128x256 tile i8 MFMA GEMM. 4 waves in 2x2; each wave 64m x 128n as 4x8
// tiles of mfma_i32_16x16x64_i8 — register blocking raised to cut LDS-pipe
// pressure (the measured limiter at 128x128: 37.6 B/cy/SIMD needed vs ~21
// available). Both operands staged via global_load_lds width=16 (register-
// streaming an operand regressed in R3: __syncthreads drains vmcnt(0)).
// LDS rows are 8 x 16B chunks, XOR-swizzled (slot = chunk ^ (row&7)) ->
// fragment ds_read_b128 is 2-lanes/bank-group = conflict-free (verified R2/R4).
__launch_bounds__(256, 2)
__global__ void gemm_i8(const signed char* __restrict__ xp,
                        const signed char* __restrict__ wp,
                        const float* __restrict__ sx,
                        const float* __restrict__ sw,
                        const float* __restrict__ sy,
                        float* __restrict__ out) {
    __shared__ __align__(16) signed char As[BM * BK];   // 16 KB
    __shared__ __align__(16) signed char Bs[BN * BK];   // 32 KB

    const int tid  = threadIdx.x;
    const int lane = tid & 63;
    const int quad = lane >> 4;    // 0..3 -> 16B k-chunk within a 64B k-step
    const int l16  = lane & 15;    // row (A) / col (B) within 16
    const int wave = tid >> 6;     // 0..3
    const int wm = wave >> 1;      // wave m (2): 64-row slab
    const int wn = wave & 1;       // wave n (2): 128-col slab
    const int bn = blockIdx.x;     // fast axis
    const int bm = blockIdx.y;

    const signed char* aG = xp + (size_t)(bm * BM) * K_DIM;
    const signed char* bG = wp + (size_t)(bn * BN) * K_DIM;

    const int csw = l16 & 7;       // fragment-read swizzle component

    // Hoisted per-thread staging offsets (loop-invariant): A = 1024 chunks,
    // B = 2048 chunks of 16B; thread handles 4 A + 8 B chunks per stage.
    int aOff[4], bOff[8];
#pragma unroll
    for (int i = 0; i < 4; i++) {
        int li = i * 256 + tid;
        int row = li >> 3, c = li & 7, g = c ^ (row & 7);
        aOff[i] = row * K_DIM + (g << 4);
    }
#pragma unroll
    for (int i = 0; i < 8; i++) {
        int li = i * 256 + tid;
        int row = li >> 3, c = li & 7, g = c ^ (row & 7);
        bOff[i] = row * K_DIM + (g << 4);
    }

    v4i acc[4][8];
#pragma unroll
    for (int i = 0; i < 4; i++)
#pragma unroll
        for (int j = 0; j < 8; j++) acc[i][j] = 0;

    for (int kk = 0; kk < K_DIM; kk += BK) {
        __syncthreads();  // protect LDS from previous iteration's readers
#pragma unroll
        for (int i = 0; i < 4; i++)
            g2lds16(aG + aOff[i] + kk, As + (i * 256 + tid) * 16);
#pragma unroll
        for (int i = 0; i < 8; i++)
            g2lds16(bG + bOff[i] + kk, Bs + (i * 256 + tid) * 16);
        __syncthreads();  // vmcnt(0) drain: staging complete

#pragma unroll
        for (int ks = 0; ks < 2; ks++) {       // two 64B k-steps per stage
            const int slot = ((ks << 2) | quad) ^ csw;
            v4i af[4], bf[8];
#pragma unroll
            for (int t = 0; t < 4; t++)
                af[t] = *(const v4i*)(As + (wm * 64 + t * 16 + l16) * BK
                                         + (slot << 4));
#pragma unroll
            for (int u = 0; u < 8; u++)
                bf[u] = *(const v4i*)(Bs + (wn * 128 + u * 16 + l16) * BK
                                         + (slot << 4));
#pragma unroll
            for (int mt = 0; mt < 4; mt++)
#pragma unroll
                for (int nt = 0; nt < 8; nt++)
                    acc[mt][nt] = __builtin_amdgcn_mfma_i32_16x16x64_i8(
                        af[mt], bf[nt], acc[mt][nt], 0, 0, 0);
        }
    }

    // Epilogue: C/D layout: col = lane&15, row = quad*4 + reg.
    const int s_base = bm * BM + wm * 64;
    const int n_base = bn * BN + wn * 128;
#pragma unroll
    for (int mt = 0; mt < 4; mt++) {
#pragma unroll
        for (int r = 0; r < 4; r++) {
            int s = s_base + mt * 16 + quad * 4 + r;
            float rs = sx[s] / sy[s];
            float* orow = out + (size_t)s * N_DIM;
#pragma unroll
            for (int nt = 0; nt < 8; nt++) {
                int n = n_base + nt * 16 + l16;
                float v = rintf((float)acc[mt][nt][r] * (rs * sw[n]));
                v = fminf(fmaxf(v, -128.f), 127.f);
                orow[n] = v;
            }
        }
    }
}

// ---------------------------------------------------------------------------
// Correctness fallback if the workspace is too small for packed operands.
__global__ void gemm_naive(const int* __restrict__ x, const int* __restrict__ w,
                           const float* __restrict__ sx, const float* __restrict__ sw,
                           const float* __restrict__ sy, float* __restrict__ out) {
    int n = blockIdx.x * blockDim.x + threadIdx.x;
    int s = blockIdx.y;
    const int4* xr = (const int4*)(x + (size_t)s * K_DIM);
    const int4* wr = (const int4*)(w + (size_t)n * K_DIM);
    int acc = 0;
    for (int k = 0; k < K_DIM / 4; k++) {
        int4 a = xr[k], b = wr[k];
        acc += a.x * b.x + a.y * b.y + a.z * b.z + a.w * b.w;
    }
    float v = rintf((float)acc * (sx[s] / sy[s] * sw[n]));
    out[(size_t)s * N_DIM + n] = fminf(fmaxf(v, -128.f), 127.f);
}

// ---------------------------------------------------------------------------
extern "C" void kernel_launch(void* const* d_in, const int* in_sizes, int n_in,
                              void* d_out, int out_size, void* d_ws, size_t ws_size,
                              hipStream_t stream) {
    const int*   x  = (const int*)d_in[0];     // [S, K] int8 values widened to int32
    const int*   wq = (const int*)d_in[1];     // [N, K]
    const float* sx = (const float*)d_in[2];   // [S]
    const float* sw = (const float*)d_in[3];   // [N]
    const float* sy = (const float*)d_in[4];   // [S]
    float* out = (float*)d_out;                // [S*N out_q] ++ [S scale_y], float32

    const size_t need = (size_t)S_DIM * K_DIM + (size_t)N_DIM * K_DIM;  // 48 MiB
    if (ws_size >= need) {
        signed char* xp = (signed char*)d_ws;
        signed char* wp = xp + (size_t)S_DIM * K_DIM;
        const int nprep = (S_DIM * K_DIM / 4) + (N_DIM * K_DIM / 4) + S_DIM;
        prep<<<dim3((nprep + 255) / 256), dim3(256), 0, stream>>>(
            x, wq, sy, (int*)xp, out);
        gemm_i8<<<dim3(N_DIM / BN, S_DIM / BM), dim3(256), 0, stream>>>(
            xp, wp, sx, sw, sy, out);
    } else {
        copy_sy<<<dim3((S_DIM + 255) / 256), dim3(256), 0, stream>>>(sy, out);
        gemm_naive<<<dim3(N_DIM / 256, S_DIM), dim3(256), 0, stream>>>(
            x, wq, sx, sw, sy, out);
    }
}